// Round 1
// baseline (224.019 us; speedup 1.0000x reference)
//
#include <hip/hip_runtime.h>

// CBOW negative-sampling loss.
// Inputs (setup_inputs order):
//   d_in[0] context   [B, C]  int32
//   d_in[1] target    [B]     int32
//   d_in[2] negatives [B, K]  int32
//   d_in[3] in_emb    [V, D]  f32
//   d_in[4] out_emb   [V, D]  f32
// Output: scalar f32 = -mean_b( log(sig(pos)+eps) + sum_k log(sig(-neg_k)+eps) )
//
// R4: single fused kernel. Half-wave (32 lanes) per b, float4/lane; all 21
// indices fetched by one predicated lane-parallel load + __shfl broadcast;
// all 21 row-gathers staged into registers (max MLP). Per-block LDS reduce
// (8 losses -> 1 partial), then last-block-done pattern (device-scope
// ACQ_REL atomic on a self-re-arming __device__ counter) sums the 2048
// partials deterministically and writes the scalar — no second dispatch,
// no memset, no reliance on poisoned workspace contents.

#define VOCAB  100000
#define DIM    128
#define B_TOT  16384
#define CWIN   10
#define K_NEG  10
#define EPS_F  1e-9f

#define BPB    8               // b's per 256-thread block (8 half-waves)
#define NBLK   (B_TOT / BPB)   // 2048 blocks

__device__ unsigned int g_done = 0;   // zero-init at load; last block re-arms

__global__ __launch_bounds__(256, 4) void cbow_loss_kernel(
    const int*   __restrict__ context,
    const int*   __restrict__ target,
    const int*   __restrict__ negatives,
    const float* __restrict__ in_emb,
    const float* __restrict__ out_emb,
    float*       __restrict__ partials,   // NBLK floats in ws
    float*       __restrict__ out)
{
    const int tid    = threadIdx.x;
    const int halfId = tid >> 5;           // 0..7
    const int sub    = tid & 31;           // lane within half-wave
    const int b      = blockIdx.x * BPB + halfId;

    const float4* in4  = (const float4*)in_emb;
    const float4* out4 = (const float4*)out_emb;

    // ---- ONE predicated load fetches all 21 indices for this half-wave ----
    // lanes 0..9  -> context[b*10+sub]
    // lanes 10..19-> negatives[b*10+(sub-10)]
    // lane  20    -> target[b]
    int myIdx = 0;
    {
        const int* p  = target;
        int        off = b;
        if (sub < CWIN)                 { p = context;   off = b * CWIN + sub; }
        else if (sub < 2 * CWIN)        { p = negatives; off = b * K_NEG + (sub - CWIN); }
        if (sub <= 2 * CWIN) myIdx = p[off];
    }

    // ---- stage all 21 row-gathers into registers (max outstanding loads) ----
    float4 cr[CWIN];
#pragma unroll
    for (int c = 0; c < CWIN; ++c) {
        const int idx = __shfl(myIdx, c, 32);            // broadcast within half
        cr[c] = in4[(idx << 5) + sub];                   // idx*32 float4s
    }
    float4 ov[K_NEG + 1];
#pragma unroll
    for (int k = 0; k <= K_NEG; ++k) {
        const int lanesrc = (k == 0) ? 2 * CWIN : (CWIN + k - 1);
        const int idx = __shfl(myIdx, lanesrc, 32);
        ov[k] = out4[(idx << 5) + sub];
    }

    // ---- context mean (lane-partial over dims 4*sub..4*sub+3) ----
    float4 cm = make_float4(0.f, 0.f, 0.f, 0.f);
#pragma unroll
    for (int c = 0; c < CWIN; ++c) {
        cm.x += cr[c].x; cm.y += cr[c].y; cm.z += cr[c].z; cm.w += cr[c].w;
    }
    cm.x *= (1.0f / CWIN); cm.y *= (1.0f / CWIN);
    cm.z *= (1.0f / CWIN); cm.w *= (1.0f / CWIN);

    // ---- lane-partial scores ----
    float s[K_NEG + 1];
#pragma unroll
    for (int k = 0; k <= K_NEG; ++k)
        s[k] = cm.x * ov[k].x + cm.y * ov[k].y + cm.z * ov[k].z + cm.w * ov[k].w;

    // ---- butterfly reduce within the 32-lane half (5 stages) ----
#pragma unroll
    for (int j = 0; j <= K_NEG; ++j) {
        float x = s[j];
#pragma unroll
        for (int off = 16; off > 0; off >>= 1)
            x += __shfl_xor(x, off, 64);   // offsets <32 stay within each half
        s[j] = x;
    }

    // ---- per-b loss ----
    float l = __logf(1.0f / (1.0f + __expf(-s[0])) + EPS_F);       // pos
#pragma unroll
    for (int k = 1; k <= K_NEG; ++k)
        l += __logf(1.0f / (1.0f + __expf(s[k])) + EPS_F);         // neg

    // ---- block-level reduction: 8 per-b losses -> 1 partial ----
    __shared__ float        lpart[BPB];
    __shared__ unsigned int s_isLast;
    if (sub == 0) lpart[halfId] = l;
    __syncthreads();

    if (tid == 0) {
        float p8 = 0.f;
#pragma unroll
        for (int i = 0; i < BPB; ++i) p8 += lpart[i];
        partials[blockIdx.x] = p8;
        // Release our partial + count finished blocks (device scope — the
        // ACQ_REL atomic orders the store above and, for the last block,
        // acquires all other blocks' partial stores across XCD L2s.
        unsigned int old = __hip_atomic_fetch_add(
            &g_done, 1u, __ATOMIC_ACQ_REL, __HIP_MEMORY_SCOPE_AGENT);
        if (old == NBLK - 1) __threadfence();   // belt-and-braces acquire
        s_isLast = (old == NBLK - 1) ? 1u : 0u;
    }
    __syncthreads();

    // ---- last block: deterministic final sum of 2048 partials ----
    if (s_isLast) {
        float x = 0.f;
#pragma unroll
        for (int j = 0; j < NBLK / 256; ++j)
            x += partials[tid + 256 * j];      // coalesced, 8 KB total
#pragma unroll
        for (int off = 32; off > 0; off >>= 1)
            x += __shfl_xor(x, off, 64);
        __shared__ float wpart[4];
        const int lane = tid & 63, wave = tid >> 6;
        if (lane == 0) wpart[wave] = x;
        __syncthreads();
        if (tid == 0) {
            out[0] = -(wpart[0] + wpart[1] + wpart[2] + wpart[3]) * (1.0f / B_TOT);
            g_done = 0;   // re-arm for the next launch (graph replay safe)
        }
    }
}

extern "C" void kernel_launch(void* const* d_in, const int* in_sizes, int n_in,
                              void* d_out, int out_size, void* d_ws, size_t ws_size,
                              hipStream_t stream) {
    const int*   context   = (const int*)  d_in[0];
    const int*   target    = (const int*)  d_in[1];
    const int*   negatives = (const int*)  d_in[2];
    const float* in_emb    = (const float*)d_in[3];
    const float* out_emb   = (const float*)d_in[4];
    float*       out       = (float*)d_out;
    float*       partials  = (float*)d_ws;   // NBLK floats; fully written each call

    cbow_loss_kernel<<<NBLK, 256, 0, stream>>>(
        context, target, negatives, in_emb, out_emb, partials, out);
}

// Round 3
// 162.511 us; speedup vs baseline: 1.3785x; 1.3785x over previous
//
#include <hip/hip_runtime.h>

// CBOW negative-sampling loss.
// Inputs (setup_inputs order):
//   d_in[0] context   [B, C]  int32
//   d_in[1] target    [B]     int32
//   d_in[2] negatives [B, K]  int32
//   d_in[3] in_emb    [V, D]  f32
//   d_in[4] out_emb   [V, D]  f32
// Output: scalar f32 = -mean_b( log(sig(pos)+eps) + sum_k log(sig(-neg_k)+eps) )
//
// R6 == R5 resubmitted (previous round failed on container acquisition,
// no kernel verdict). Fused single kernel, NO cache-maintenance atomics.
//
// R4's ACQ_REL/AGENT atomic per block emitted buffer_wbl2 + buffer_inv
// (L2 writeback+invalidate) 2048x, destroying the L2 reuse the gathers
// depend on (126 us, HBM 8.5%, FETCH unchanged). This version communicates
// ONLY through relaxed agent-scope atomics (performed at the per-address
// coherence point -> coherent across XCDs with zero cache flushes):
//   - each block atomicAdd's its float partial into g_acc
//   - completion of that RMW is forced (empty asm consuming the returned
//     value => s_waitcnt vmcnt(0)) before the g_done counter increment,
//     giving performed-before ordering without release semantics
//   - last block (counter == NBLK-1) atomically loads g_acc, writes the
//     scalar, and re-arms both globals with relaxed atomic stores.
// No workspace use at all. Hot gather path identical to R3/R4.

#define VOCAB  100000
#define DIM    128
#define B_TOT  16384
#define CWIN   10
#define K_NEG  10
#define EPS_F  1e-9f

#define BPB    8               // b's per 256-thread block (8 half-waves)
#define NBLK   (B_TOT / BPB)   // 2048 blocks

__device__ float        g_acc  = 0.f;   // zero at module load; last block re-arms
__device__ unsigned int g_done = 0;

__global__ __launch_bounds__(256, 4) void cbow_loss_kernel(
    const int*   __restrict__ context,
    const int*   __restrict__ target,
    const int*   __restrict__ negatives,
    const float* __restrict__ in_emb,
    const float* __restrict__ out_emb,
    float*       __restrict__ out)
{
    const int tid    = threadIdx.x;
    const int halfId = tid >> 5;           // 0..7
    const int sub    = tid & 31;           // lane within half-wave
    const int b      = blockIdx.x * BPB + halfId;

    const float4* in4  = (const float4*)in_emb;
    const float4* out4 = (const float4*)out_emb;

    // ---- ONE predicated load fetches all 21 indices for this half-wave ----
    // lanes 0..9  -> context[b*10+sub]
    // lanes 10..19-> negatives[b*10+(sub-10)]
    // lane  20    -> target[b]
    int myIdx = 0;
    {
        const int* p  = target;
        int        off = b;
        if (sub < CWIN)                 { p = context;   off = b * CWIN + sub; }
        else if (sub < 2 * CWIN)        { p = negatives; off = b * K_NEG + (sub - CWIN); }
        if (sub <= 2 * CWIN) myIdx = p[off];
    }

    // ---- stage all 21 row-gathers into registers (max outstanding loads) ----
    float4 cr[CWIN];
#pragma unroll
    for (int c = 0; c < CWIN; ++c) {
        const int idx = __shfl(myIdx, c, 32);            // broadcast within half
        cr[c] = in4[(idx << 5) + sub];                   // idx*32 float4s
    }
    float4 ov[K_NEG + 1];
#pragma unroll
    for (int k = 0; k <= K_NEG; ++k) {
        const int lanesrc = (k == 0) ? 2 * CWIN : (CWIN + k - 1);
        const int idx = __shfl(myIdx, lanesrc, 32);
        ov[k] = out4[(idx << 5) + sub];
    }

    // ---- context mean (lane-partial over dims 4*sub..4*sub+3) ----
    float4 cm = make_float4(0.f, 0.f, 0.f, 0.f);
#pragma unroll
    for (int c = 0; c < CWIN; ++c) {
        cm.x += cr[c].x; cm.y += cr[c].y; cm.z += cr[c].z; cm.w += cr[c].w;
    }
    cm.x *= (1.0f / CWIN); cm.y *= (1.0f / CWIN);
    cm.z *= (1.0f / CWIN); cm.w *= (1.0f / CWIN);

    // ---- lane-partial scores ----
    float s[K_NEG + 1];
#pragma unroll
    for (int k = 0; k <= K_NEG; ++k)
        s[k] = cm.x * ov[k].x + cm.y * ov[k].y + cm.z * ov[k].z + cm.w * ov[k].w;

    // ---- butterfly reduce within the 32-lane half (5 stages) ----
#pragma unroll
    for (int j = 0; j <= K_NEG; ++j) {
        float x = s[j];
#pragma unroll
        for (int off = 16; off > 0; off >>= 1)
            x += __shfl_xor(x, off, 64);   // offsets <32 stay within each half
        s[j] = x;
    }

    // ---- per-b loss ----
    float l = __logf(1.0f / (1.0f + __expf(-s[0])) + EPS_F);       // pos
#pragma unroll
    for (int k = 1; k <= K_NEG; ++k)
        l += __logf(1.0f / (1.0f + __expf(s[k])) + EPS_F);         // neg

    // ---- block-level reduction: 8 per-b losses -> 1 partial ----
    __shared__ float lpart[BPB];
    if (sub == 0) lpart[halfId] = l;
    __syncthreads();

    if (tid == 0) {
        float p8 = 0.f;
#pragma unroll
        for (int i = 0; i < BPB; ++i) p8 += lpart[i];

        // Accumulate at the coherence point (no cache flushes).
        float oldv = __hip_atomic_fetch_add(
            &g_acc, p8, __ATOMIC_RELAXED, __HIP_MEMORY_SCOPE_AGENT);
        // Consuming the returned value forces s_waitcnt vmcnt(0): our g_acc
        // RMW is globally performed before the counter increment issues.
        asm volatile("" : : "v"(oldv) : "memory");

        unsigned int cnt = __hip_atomic_fetch_add(
            &g_done, 1u, __ATOMIC_RELAXED, __HIP_MEMORY_SCOPE_AGENT);
        if (cnt == NBLK - 1) {
            // Every other block's g_acc add was performed before its g_done
            // increment; we observed all increments -> total is complete.
            float tot = __hip_atomic_load(
                &g_acc, __ATOMIC_RELAXED, __HIP_MEMORY_SCOPE_AGENT);
            out[0] = -tot * (1.0f / B_TOT);
            // Re-arm for the next (graph-replayed) launch.
            __hip_atomic_store(&g_acc, 0.f,
                               __ATOMIC_RELAXED, __HIP_MEMORY_SCOPE_AGENT);
            __hip_atomic_store(&g_done, 0u,
                               __ATOMIC_RELAXED, __HIP_MEMORY_SCOPE_AGENT);
        }
    }
}

extern "C" void kernel_launch(void* const* d_in, const int* in_sizes, int n_in,
                              void* d_out, int out_size, void* d_ws, size_t ws_size,
                              hipStream_t stream) {
    const int*   context   = (const int*)  d_in[0];
    const int*   target    = (const int*)  d_in[1];
    const int*   negatives = (const int*)  d_in[2];
    const float* in_emb    = (const float*)d_in[3];
    const float* out_emb   = (const float*)d_in[4];
    float*       out       = (float*)d_out;

    cbow_loss_kernel<<<NBLK, 256, 0, stream>>>(
        context, target, negatives, in_emb, out_emb, out);
}

// Round 4
// 131.007 us; speedup vs baseline: 1.7100x; 1.2405x over previous
//
#include <hip/hip_runtime.h>

// CBOW negative-sampling loss.
// Inputs (setup_inputs order):
//   d_in[0] context   [B, C]  int32
//   d_in[1] target    [B]     int32
//   d_in[2] negatives [B, K]  int32
//   d_in[3] in_emb    [V, D]  f32
//   d_in[4] out_emb   [V, D]  f32
// Output: scalar f32 = -mean_b( log(sig(pos)+eps) + sum_k log(sig(-neg_k)+eps) )
//
// R7: two-kernel again (fusion + same-line atomics was a net -34us: 4096
// dependent RMWs to one cache line). Main kernel change: VGPR_Count=36 in
// R4/R6 proved the compiler was NOT staging the 21 float4 gathers (needs
// >=84 VGPRs) -- it recycled ~5 regs, turning 21 independent loads into
// ~4-5 dependent latency rounds per half-wave. A sched_barrier(0) after
// all load issues forces 21-deep MLP per half-wave (launch_bounds(256,4)
// budget = 128 VGPR, enough for ~105). Per-block LDS reduce shrinks the
// intermediate to 2048 floats (8 KB); finalize is one small block.

#define VOCAB  100000
#define DIM    128
#define B_TOT  16384
#define CWIN   10
#define K_NEG  10
#define EPS_F  1e-9f

#define BPB    8               // b's per 256-thread block (8 half-waves)
#define NBLK   (B_TOT / BPB)   // 2048 blocks

__global__ __launch_bounds__(256, 4) void cbow_loss_kernel(
    const int*   __restrict__ context,
    const int*   __restrict__ target,
    const int*   __restrict__ negatives,
    const float* __restrict__ in_emb,
    const float* __restrict__ out_emb,
    float*       __restrict__ partials)    // NBLK floats in ws
{
    const int tid    = threadIdx.x;
    const int halfId = tid >> 5;           // 0..7
    const int sub    = tid & 31;           // lane within half-wave
    const int b      = blockIdx.x * BPB + halfId;

    const float4* in4  = (const float4*)in_emb;
    const float4* out4 = (const float4*)out_emb;

    // ---- ONE predicated load fetches all 21 indices for this half-wave ----
    // lanes 0..9  -> context[b*10+sub]
    // lanes 10..19-> negatives[b*10+(sub-10)]
    // lane  20    -> target[b]
    int myIdx = 0;
    {
        const int* p  = target;
        int        off = b;
        if (sub < CWIN)                 { p = context;   off = b * CWIN + sub; }
        else if (sub < 2 * CWIN)        { p = negatives; off = b * K_NEG + (sub - CWIN); }
        if (sub <= 2 * CWIN) myIdx = p[off];
    }

    // ---- stage all 21 row-gathers into registers: issue EVERY load before
    // any consumer. The sched_barrier(0) forbids the scheduler from sinking
    // loads past it, so all 21 global_load_dwordx4 are in flight at once
    // (VGPR cost ~84 regs; launch_bounds(256,4) caps at 128). ----
    float4 cr[CWIN];
#pragma unroll
    for (int c = 0; c < CWIN; ++c) {
        const int idx = __shfl(myIdx, c, 32);            // broadcast within half
        cr[c] = in4[(idx << 5) + sub];                   // idx*32 float4s
    }
    float4 ov[K_NEG + 1];
#pragma unroll
    for (int k = 0; k <= K_NEG; ++k) {
        const int lanesrc = (k == 0) ? 2 * CWIN : (CWIN + k - 1);
        const int idx = __shfl(myIdx, lanesrc, 32);
        ov[k] = out4[(idx << 5) + sub];
    }
    __builtin_amdgcn_sched_barrier(0);     // all 21 loads issued before any use

    // ---- context mean (lane-partial over dims 4*sub..4*sub+3) ----
    float4 cm = make_float4(0.f, 0.f, 0.f, 0.f);
#pragma unroll
    for (int c = 0; c < CWIN; ++c) {
        cm.x += cr[c].x; cm.y += cr[c].y; cm.z += cr[c].z; cm.w += cr[c].w;
    }
    cm.x *= (1.0f / CWIN); cm.y *= (1.0f / CWIN);
    cm.z *= (1.0f / CWIN); cm.w *= (1.0f / CWIN);

    // ---- lane-partial scores ----
    float s[K_NEG + 1];
#pragma unroll
    for (int k = 0; k <= K_NEG; ++k)
        s[k] = cm.x * ov[k].x + cm.y * ov[k].y + cm.z * ov[k].z + cm.w * ov[k].w;

    // ---- butterfly reduce within the 32-lane half (5 stages) ----
#pragma unroll
    for (int j = 0; j <= K_NEG; ++j) {
        float x = s[j];
#pragma unroll
        for (int off = 16; off > 0; off >>= 1)
            x += __shfl_xor(x, off, 64);   // offsets <32 stay within each half
        s[j] = x;
    }

    // ---- per-b loss ----
    float l = __logf(1.0f / (1.0f + __expf(-s[0])) + EPS_F);       // pos
#pragma unroll
    for (int k = 1; k <= K_NEG; ++k)
        l += __logf(1.0f / (1.0f + __expf(s[k])) + EPS_F);         // neg

    // ---- block reduce: 8 per-b losses -> 1 partial (plain store, no atomics)
    __shared__ float lpart[BPB];
    if (sub == 0) lpart[halfId] = l;
    __syncthreads();
    if (tid == 0) {
        float p8 = 0.f;
#pragma unroll
        for (int i = 0; i < BPB; ++i) p8 += lpart[i];
        partials[blockIdx.x] = p8;
    }
}

__global__ __launch_bounds__(256) void finalize_kernel(
    const float* __restrict__ partials,    // NBLK floats
    float*       __restrict__ out)
{
    const int tid  = threadIdx.x;
    const int lane = tid & 63;
    const int wave = tid >> 6;

    float x = 0.f;
#pragma unroll
    for (int j = 0; j < NBLK / 256; ++j)
        x += partials[tid + 256 * j];      // coalesced, 8 KB total

#pragma unroll
    for (int off = 32; off > 0; off >>= 1)
        x += __shfl_xor(x, off, 64);

    __shared__ float part[4];
    if (lane == 0) part[wave] = x;
    __syncthreads();
    if (tid == 0)
        out[0] = -(part[0] + part[1] + part[2] + part[3]) * (1.0f / B_TOT);
}

extern "C" void kernel_launch(void* const* d_in, const int* in_sizes, int n_in,
                              void* d_out, int out_size, void* d_ws, size_t ws_size,
                              hipStream_t stream) {
    const int*   context   = (const int*)  d_in[0];
    const int*   target    = (const int*)  d_in[1];
    const int*   negatives = (const int*)  d_in[2];
    const float* in_emb    = (const float*)d_in[3];
    const float* out_emb   = (const float*)d_in[4];
    float*       out       = (float*)d_out;
    float*       partials  = (float*)d_ws;   // NBLK floats; fully written each call

    cbow_loss_kernel<<<NBLK, 256, 0, stream>>>(
        context, target, negatives, in_emb, out_emb, partials);
    finalize_kernel<<<1, 256, 0, stream>>>(partials, out);
}